// Round 11
// baseline (342.870 us; speedup 1.0000x reference)
//
#include <hip/hip_runtime.h>
#include <float.h>

// Problem constants
#define N_PTS    32768
#define N_CODES  2048
#define DIM      256
#define S_STRIDE 4096
#define B_STRIDE 1048576
#define N_ELEM   8388608

#define THR 2.5e-4f   // 2x max |screen - np| score deviation (~6e-5) with 2x slack

// ws layout (bytes), 16-aligned
#define WS_PARTIAL 0          // float[64]
#define WS_CNT     256        // int[2]: nlight, nheavy
#define WS_E2      512        // float[2048]        -> 8704
#define WS_Z2      8704       // float[32768]       -> 139776
#define WS_EBH     139776     // bf16[2048*256]     -> 1188352
#define WS_EBL     1188352    // bf16[2048*256]     -> 2236928
#define WS_ZT      2236928    // bf16[32768*256]    -> 19014144
#define WS_TS12    19014144   // float2[32768*32]   -> 27402624
#define WS_TS2     27402624   // float[32768*32]    -> 31596928
#define WS_LIGHT   31596928   // int[32768]         -> 31728000
#define WS_HEAVY   31728000   // int[32768]         -> 31859072

typedef unsigned short ushort_t;
typedef short bf16x8 __attribute__((ext_vector_type(8)));
typedef float f32x4 __attribute__((ext_vector_type(4)));

__device__ __forceinline__ ushort_t f2bf(float v) {   // RNE fp32->bf16
    const unsigned u = __float_as_uint(v);
    return (ushort_t)((u + 0x7FFFu + ((u >> 16) & 1u)) >> 16);
}
__device__ __forceinline__ float bf2f(ushort_t h) { return __uint_as_float(((unsigned)h) << 16); }

__device__ __forceinline__ void async_copy16(void* lds, const void* g) {
    __builtin_amdgcn_global_load_lds(
        (const __attribute__((address_space(1))) unsigned int*)g,
        (__attribute__((address_space(3))) unsigned int*)lds, 16, 0, 0);
}

// np-exact score: ascending-c fmaf chain + fl(fl(z2+e2)-2*dot)  [validated R4-R9]
__device__ __forceinline__ float np_score(const float* zr, const float* er, float z2n, float e2k) {
    float dot = 0.f;
    #pragma unroll 8
    for (int c4 = 0; c4 < 64; ++c4) {
        const float4 ev = reinterpret_cast<const float4*>(er)[c4];
        const float4 zv = *reinterpret_cast<const float4*>(zr + c4 * 4);
        dot = fmaf(zv.x, ev.x, dot);
        dot = fmaf(zv.y, ev.y, dot);
        dot = fmaf(zv.z, ev.z, dot);
        dot = fmaf(zv.w, ev.w, dot);
    }
    const float A = __fadd_rn(z2n, e2k);
    return __fsub_rn(A, __fmul_rn(2.f, dot));
}

// emb fp32 -> (eh, el) split bf16; zero counters/partials.
__global__ void conv_emb_kernel(const float* __restrict__ emb, ushort_t* __restrict__ ebh,
                                ushort_t* __restrict__ ebl, float* __restrict__ partial,
                                int* __restrict__ cnt) {
    const int gid = blockIdx.x * 256 + threadIdx.x;
    if (blockIdx.x == 0) {
        if (threadIdx.x < 64) partial[threadIdx.x] = 0.f;
        if (threadIdx.x < 2) cnt[threadIdx.x] = 0;
    }
    const float4 u = *reinterpret_cast<const float4*>(emb + (size_t)gid * 4);
    ushort4 h, l;
    h.x = f2bf(u.x); l.x = f2bf(__fsub_rn(u.x, bf2f(h.x)));
    h.y = f2bf(u.y); l.y = f2bf(__fsub_rn(u.y, bf2f(h.y)));
    h.z = f2bf(u.z); l.z = f2bf(__fsub_rn(u.z, bf2f(h.z)));
    h.w = f2bf(u.w); l.w = f2bf(__fsub_rn(u.w, bf2f(h.w)));
    *reinterpret_cast<ushort4*>(ebh + (size_t)gid * 4) = h;
    *reinterpret_cast<ushort4*>(ebl + (size_t)gid * 4) = l;
}

// e2[k]: np pairwise sum of emb[k]^2  [validated]
__global__ void e2_kernel(const float* __restrict__ emb, float* __restrict__ e2) {
    const int k = blockIdx.x * 256 + threadIdx.x;
    const float* base = emb + (size_t)k * DIM;
    float half[2];
    #pragma unroll
    for (int h = 0; h < 2; ++h) {
        float r[8];
        #pragma unroll
        for (int j = 0; j < 8; ++j) { const float v = base[h * 128 + j]; r[j] = __fmul_rn(v, v); }
        for (int t = 8; t < 128; t += 8)
            #pragma unroll
            for (int j = 0; j < 8; ++j) {
                const float v = base[h * 128 + t + j];
                r[j] = __fadd_rn(r[j], __fmul_rn(v, v));
            }
        half[h] = __fadd_rn(__fadd_rn(__fadd_rn(r[0], r[1]), __fadd_rn(r[2], r[3])),
                            __fadd_rn(__fadd_rn(r[4], r[5]), __fadd_rn(r[6], r[7])));
    }
    e2[k] = __fadd_rn(half[0], half[1]);
}

// z2[n]: np pairwise sum of z_flat[n]^2  [validated]
__global__ void z2_kernel(const float* __restrict__ z, float* __restrict__ z2) {
    const int n = blockIdx.x * 256 + threadIdx.x;
    const int b = n >> 12, s = n & 4095;
    const float* base = z + (size_t)b * B_STRIDE + s;
    float half[2];
    #pragma unroll
    for (int h = 0; h < 2; ++h) {
        float r[8];
        #pragma unroll
        for (int j = 0; j < 8; ++j) {
            const float v = base[(size_t)(h * 128 + j) * S_STRIDE];
            r[j] = __fmul_rn(v, v);
        }
        for (int t = 8; t < 128; t += 8)
            #pragma unroll
            for (int j = 0; j < 8; ++j) {
                const float v = base[(size_t)(h * 128 + t + j) * S_STRIDE];
                r[j] = __fadd_rn(r[j], __fmul_rn(v, v));
            }
        half[h] = __fadd_rn(__fadd_rn(__fadd_rn(r[0], r[1]), __fadd_rn(r[2], r[3])),
                            __fadd_rn(__fadd_rn(r[4], r[5]), __fadd_rn(r[6], r[7])));
    }
    z2[n] = __fadd_rn(half[0], half[1]);
}

// z -> z_t bf16 [n][c], 64x64 LDS transpose tiles  [validated]
__global__ void transpose_kernel(const float* __restrict__ z, ushort_t* __restrict__ zt) {
    __shared__ ushort_t lt[64][72];
    const int bx = blockIdx.x;
    const int b = bx >> 8, cg = (bx >> 6) & 3, sg = bx & 63;
    const int c0 = cg * 64, s0 = sg * 64;
    const int t = threadIdx.x;
    {
        const int cl = t >> 4, s4 = t & 15;
        #pragma unroll
        for (int j = 0; j < 4; ++j) {
            const int c = cl + 16 * j;
            const float4 u = *reinterpret_cast<const float4*>(
                z + (size_t)b * B_STRIDE + (size_t)(c0 + c) * S_STRIDE + s0 + s4 * 4);
            ushort4 v; v.x = f2bf(u.x); v.y = f2bf(u.y); v.z = f2bf(u.z); v.w = f2bf(u.w);
            *reinterpret_cast<ushort4*>(&lt[c][s4 * 4]) = v;
        }
    }
    __syncthreads();
    {
        const int sl = t >> 4, c4 = t & 15;
        #pragma unroll
        for (int j = 0; j < 4; ++j) {
            const int s = sl + 16 * j;
            ushort4 v;
            v.x = lt[c4 * 4 + 0][s]; v.y = lt[c4 * 4 + 1][s];
            v.z = lt[c4 * 4 + 2][s]; v.w = lt[c4 * 4 + 3][s];
            *reinterpret_cast<ushort4*>(zt + (size_t)(b * 4096 + s0 + s) * DIM + c0 + c4 * 4) = v;
        }
    }
}

// DPP helpers (VALU cross-lane; xor1, xor2, mirror-in-8, mirror-in-16 = full 16-lane reduce)
#define DPP_F(dst, src, CTRL) \
    dst = __uint_as_float(__builtin_amdgcn_mov_dpp(__float_as_uint(src), CTRL, 0xF, 0xF, true))
#define MERGE_STAGE(CTRL) { \
    float om1, oi1, om2; \
    DPP_F(om1, m1, CTRL); DPP_F(oi1, i1, CTRL); DPP_F(om2, m2, CTRL); \
    const bool take = (om1 < m1) || (om1 == m1 && oi1 < i1); \
    const float l1 = take ? m1 : om1, li = take ? i1 : oi1; \
    const float o2 = take ? om2 : m2; \
    if (take) { m1 = om1; i1 = oi1; } \
    m2 = (l1 <= o2) ? l1 : o2; (void)li; }

// Screen: BM=128 pts x BN=256 codes, BK=32, MFMA zh*eh + zh*el into shared acc.
// Emits per-(point, 64-code group g = bn*4 + wv): (min1, idx1) and min2 of the
// full ref-formula score fl(fl(z2+e2) - 2*dot).  Group == wave: race-free.
__global__ __launch_bounds__(256, 2) void screen_kernel(
    const ushort_t* __restrict__ zt, const ushort_t* __restrict__ ebh,
    const ushort_t* __restrict__ ebl, const float* __restrict__ e2,
    const float* __restrict__ z2, float2* __restrict__ ts12, float* __restrict__ ts2)
{
    __shared__ char lds[40960];      // A zh: [0,8K); B eh: [8K,24K); B el: [24K,40K)
    __shared__ float e2s[256];
    __shared__ float z2s[128];
    const int tid = threadIdx.x;
    const int bm = blockIdx.x & 255, bn = blockIdx.x >> 8;
    const int n0 = bm * 128, k0 = bn * 256;
    e2s[tid] = e2[k0 + tid];
    if (tid < 128) z2s[tid] = z2[n0 + tid];
    const int wv = tid >> 6, lane = tid & 63;
    const int col = lane & 15, quad = lane >> 4;

    f32x4 acc[8][4];
    #pragma unroll
    for (int i = 0; i < 8; ++i)
        #pragma unroll
        for (int j = 0; j < 4; ++j) acc[i][j] = (f32x4){0.f, 0.f, 0.f, 0.f};

    for (int kc = 0; kc < 8; ++kc) {     // K = 8 x 32
        __syncthreads();
        #pragma unroll
        for (int it = 0; it < 10; ++it) {    // 2560 x 16B chunks: A 512, Bh 1024, Bl 1024
            const int L = tid + it * 256;
            const ushort_t* src;
            if (L < 512) {
                const int row = L >> 2, pc = L & 3, c = pc ^ (row & 3);
                src = zt + ((size_t)(n0 + row) * DIM + kc * 32 + c * 8);
            } else if (L < 1536) {
                const int L2 = L - 512;
                const int row = L2 >> 2, pc = L2 & 3, c = pc ^ (row & 3);
                src = ebh + ((size_t)(k0 + row) * DIM + kc * 32 + c * 8);
            } else {
                const int L3 = L - 1536;
                const int row = L3 >> 2, pc = L3 & 3, c = pc ^ (row & 3);
                src = ebl + ((size_t)(k0 + row) * DIM + kc * 32 + c * 8);
            }
            async_copy16(lds + L * 16, src);   // lds dst linear in lane (wave-uniform base)
        }
        __syncthreads();
        bf16x8 af[8], bh[4], bl[4];
        #pragma unroll
        for (int i = 0; i < 8; ++i) {
            const int arow = i * 16 + col, pcA = quad ^ (arow & 3);
            af[i] = *reinterpret_cast<const bf16x8*>(lds + (arow * 4 + pcA) * 16);
        }
        #pragma unroll
        for (int j = 0; j < 4; ++j) {
            const int brow = wv * 64 + j * 16 + col, pcB = quad ^ (brow & 3);
            bh[j] = *reinterpret_cast<const bf16x8*>(lds + 8192 + (brow * 4 + pcB) * 16);
            bl[j] = *reinterpret_cast<const bf16x8*>(lds + 24576 + (brow * 4 + pcB) * 16);
        }
        #pragma unroll
        for (int i = 0; i < 8; ++i)
            #pragma unroll
            for (int j = 0; j < 4; ++j) {
                acc[i][j] = __builtin_amdgcn_mfma_f32_16x16x32_bf16(af[i], bh[j], acc[i][j], 0, 0, 0);
                acc[i][j] = __builtin_amdgcn_mfma_f32_16x16x32_bf16(af[i], bl[j], acc[i][j], 0, 0, 0);
            }
    }

    // epilogue: ref-formula scores; per-point (min1,idx1,min2) over THIS WAVE's 64 codes
    const int g = bn * 4 + wv;           // 64-code group, one per wave -> no cross-wave race
    float e2c[4], kf[4];
    #pragma unroll
    for (int j = 0; j < 4; ++j) {
        e2c[j] = e2s[wv * 64 + j * 16 + col];
        kf[j] = (float)(k0 + wv * 64 + j * 16 + col);
    }
    #pragma unroll
    for (int i = 0; i < 8; ++i) {
        #pragma unroll
        for (int r = 0; r < 4; ++r) {
            const float z2v = z2s[i * 16 + quad * 4 + r];
            float s[4];
            #pragma unroll
            for (int j = 0; j < 4; ++j) {
                const float A = __fadd_rn(z2v, e2c[j]);
                s[j] = __fsub_rn(A, __fmul_rn(2.f, acc[i][j][r]));
            }
            float m1 = s[0], i1 = kf[0], m2 = FLT_MAX;
            #pragma unroll
            for (int j = 1; j < 4; ++j) {
                if (s[j] < m1) { m2 = m1; m1 = s[j]; i1 = kf[j]; }
                else if (s[j] < m2) m2 = s[j];
            }
            MERGE_STAGE(0xB1)    // quad_perm xor1
            MERGE_STAGE(0x4E)    // quad_perm xor2
            MERGE_STAGE(0x141)   // row_half_mirror (pairs across quads within 8)
            MERGE_STAGE(0x140)   // row_mirror (pairs across halves within 16)
            if (col == 0) {
                const int n = n0 + i * 16 + quad * 4 + r;
                float2 o; o.x = m1; o.y = i1;
                ts12[(size_t)n * 32 + g] = o;
                ts2[(size_t)n * 32 + g] = m2;
            }
        }
    }
}

// Merge: resolve unambiguous points; route rest to light (candidate re-score) /
// heavy (group rescan).
__global__ void merge_kernel(const float2* __restrict__ ts12, const float* __restrict__ ts2,
                             float* __restrict__ out_idx, int* __restrict__ cnt,
                             int* __restrict__ light, int* __restrict__ heavy)
{
    const int n = blockIdx.x * 256 + threadIdx.x;
    float m1 = FLT_MAX, i1 = 0.f;
    #pragma unroll
    for (int j = 0; j < 32; ++j) {
        const float2 t = ts12[(size_t)n * 32 + j];
        if (t.x < m1 || (t.x == m1 && t.y < i1)) { m1 = t.x; i1 = t.y; }
    }
    const float thr = m1 + THR;
    int cand = 0; bool anyM2 = false;
    #pragma unroll
    for (int j = 0; j < 32; ++j) {
        cand += (ts12[(size_t)n * 32 + j].x <= thr);
        anyM2 = anyM2 || (ts2[(size_t)n * 32 + j] <= thr);
    }
    if (!anyM2 && cand == 1) out_idx[n] = i1;
    else if (anyM2) heavy[atomicAdd(&cnt[1], 1)] = n;
    else light[atomicAdd(&cnt[0], 1)] = n;
}

// Light: np-exact over group-min1 candidates within thr (one wave per point).
__global__ __launch_bounds__(256) void light_kernel(
    const float* __restrict__ z, const float* __restrict__ emb,
    const float* __restrict__ z2, const float* __restrict__ e2,
    const float2* __restrict__ ts12, const int* __restrict__ cnt,
    const int* __restrict__ light, float* __restrict__ out_idx)
{
    __shared__ float zsl[4][260];
    const int wv = threadIdx.x >> 6, lane = threadIdx.x & 63;
    const int nl = cnt[0];
    for (int slot = blockIdx.x * 4 + wv; slot < nl; slot += 2048) {
        const int n = light[slot];
        const int b = n >> 12, s = n & 4095;
        #pragma unroll
        for (int q = 0; q < 4; ++q)
            zsl[wv][lane + 64 * q] = z[(size_t)b * B_STRIDE + (size_t)(lane + 64 * q) * S_STRIDE + s];
        float m1j = FLT_MAX, i1j = 0.f;
        if (lane < 32) {
            const float2 t = ts12[(size_t)n * 32 + lane];
            m1j = t.x; i1j = t.y;
        }
        float gm1 = m1j;
        #pragma unroll
        for (int off = 1; off < 64; off <<= 1) gm1 = fminf(gm1, __shfl_xor(gm1, off));
        const float thr = gm1 + THR;
        float bs = FLT_MAX; int bk = 0x7FFFFFFF;
        if (lane < 32 && m1j <= thr) {
            const int k = (int)i1j;
            bs = np_score(zsl[wv], emb + (size_t)k * DIM, z2[n], e2[k]);
            bk = k;
        }
        #pragma unroll
        for (int off = 1; off < 64; off <<= 1) {
            const float os = __shfl_xor(bs, off);
            const int ok = __shfl_xor(bk, off);
            if (os < bs || (os == bs && ok < bk)) { bs = os; bk = ok; }
        }
        if (lane == 0) out_idx[n] = (float)bk;
    }
}

// Heavy: np-exact rescan of groups with min2 <= thr (64 codes, one wave per
// group, 4 concurrent) + group-min1 candidates.
__global__ __launch_bounds__(256) void heavy_kernel(
    const float* __restrict__ z, const float* __restrict__ emb,
    const float* __restrict__ z2, const float* __restrict__ e2,
    const float2* __restrict__ ts12, const float* __restrict__ ts2,
    const int* __restrict__ cnt, const int* __restrict__ heavy, float* __restrict__ out_idx)
{
    __shared__ float zs[DIM];
    __shared__ float m1s[32], i1s[32], m2s[32];
    __shared__ int flist[32];
    __shared__ int nf;
    __shared__ float rs[256];
    __shared__ int rk[256];
    const int tid = threadIdx.x;
    const int wv = tid >> 6, lane = tid & 63;
    const int nh = cnt[1];
    for (int it = blockIdx.x; it < nh; it += gridDim.x) {
        __syncthreads();
        const int n = heavy[it];
        const int b = n >> 12, s = n & 4095;
        zs[tid] = z[(size_t)b * B_STRIDE + (size_t)tid * S_STRIDE + s];
        if (tid < 32) {
            const float2 t = ts12[(size_t)n * 32 + tid];
            m1s[tid] = t.x; i1s[tid] = t.y;
            m2s[tid] = ts2[(size_t)n * 32 + tid];
        }
        if (tid == 0) nf = 0;
        __syncthreads();
        float gm1 = m1s[0];
        #pragma unroll
        for (int j = 1; j < 32; ++j) gm1 = fminf(gm1, m1s[j]);
        const float thr = gm1 + THR;
        if (tid == 0) {
            int c = 0;
            for (int j = 0; j < 32; ++j) if (m2s[j] <= thr) flist[c++] = j;
            nf = c;
        }
        __syncthreads();
        const float z2n = z2[n];
        float bs = FLT_MAX; int bk = 0x7FFFFFFF;
        if (tid < 32 && m1s[tid] <= thr) {       // candidate group min1s
            const int k = (int)i1s[tid];
            bs = np_score(zs, emb + (size_t)k * DIM, z2n, e2[k]);
            bk = k;
        }
        for (int base = 0; base < nf; base += 4) {   // flagged groups: full 64-code rescan
            const int fidx = base + wv;
            if (fidx < nf) {
                const int k = flist[fidx] * 64 + lane;
                const float sc = np_score(zs, emb + (size_t)k * DIM, z2n, e2[k]);
                if (sc < bs || (sc == bs && k < bk)) { bs = sc; bk = k; }
            }
        }
        rs[tid] = bs; rk[tid] = bk;
        __syncthreads();
        for (int st = 128; st > 0; st >>= 1) {
            if (tid < st) {
                const float ov = rs[tid + st]; const int ok = rk[tid + st];
                if (ov < rs[tid] || (ov == rs[tid] && ok < rk[tid])) { rs[tid] = ov; rk[tid] = ok; }
            }
            __syncthreads();
        }
        if (tid == 0) out_idx[n] = (float)rk[0];
    }
}

// Gather z_q (faithful misaligned reshape) + fused loss  [validated]
__global__ void gather_loss_kernel(const float* __restrict__ z, const float* __restrict__ emb,
                                   const float* __restrict__ out_idx, float* __restrict__ outf,
                                   float* __restrict__ partial)
{
    const int gid = blockIdx.x * 256 + threadIdx.x;
    const size_t m0 = (size_t)gid * 4;
    const int row = (int)(m0 >> 8), col = (int)(m0 & 255);
    const int id = (int)out_idx[row];
    const float4 q = *reinterpret_cast<const float4*>(emb + (size_t)id * DIM + col);
    const float4 zv = *reinterpret_cast<const float4*>(z + m0);
    *reinterpret_cast<float4*>(outf + m0) = q;
    const float d0 = q.x - zv.x, d1 = q.y - zv.y, d2 = q.z - zv.z, d3 = q.w - zv.w;
    float accl = d0 * d0 + d1 * d1 + d2 * d2 + d3 * d3;
    #pragma unroll
    for (int off = 32; off > 0; off >>= 1) accl += __shfl_xor(accl, off);
    __shared__ float part[4];
    const int lane = threadIdx.x & 63, w64 = threadIdx.x >> 6;
    if (lane == 0) part[w64] = accl;
    __syncthreads();
    if (threadIdx.x == 0)
        atomicAdd(&partial[blockIdx.x & 63], part[0] + part[1] + part[2] + part[3]);
}

__global__ void finalize_kernel(const float* __restrict__ partial, float* __restrict__ out_loss) {
    float v = partial[threadIdx.x];
    #pragma unroll
    for (int off = 1; off < 64; off <<= 1) v += __shfl_xor(v, off);
    if (threadIdx.x == 0)
        *out_loss = v * 1.25f / (float)N_ELEM;
}

extern "C" void kernel_launch(void* const* d_in, const int* in_sizes, int n_in,
                              void* d_out, int out_size, void* d_ws, size_t ws_size,
                              hipStream_t stream) {
    const float* z = (const float*)d_in[0];
    const float* emb = (const float*)d_in[1];
    char* ws = (char*)d_ws;
    float* partial = (float*)(ws + WS_PARTIAL);
    int* cnt = (int*)(ws + WS_CNT);
    float* e2 = (float*)(ws + WS_E2);
    float* z2 = (float*)(ws + WS_Z2);
    ushort_t* ebh = (ushort_t*)(ws + WS_EBH);
    ushort_t* ebl = (ushort_t*)(ws + WS_EBL);
    ushort_t* zt = (ushort_t*)(ws + WS_ZT);
    float2* ts12 = (float2*)(ws + WS_TS12);
    float* ts2 = (float*)(ws + WS_TS2);
    int* light = (int*)(ws + WS_LIGHT);
    int* heavy = (int*)(ws + WS_HEAVY);
    float* outf = (float*)d_out;
    float* out_loss = outf + N_ELEM;
    float* out_idx = outf + N_ELEM + 1;

    conv_emb_kernel<<<512, 256, 0, stream>>>(emb, ebh, ebl, partial, cnt);
    e2_kernel<<<N_CODES / 256, 256, 0, stream>>>(emb, e2);
    z2_kernel<<<N_PTS / 256, 256, 0, stream>>>(z, z2);
    transpose_kernel<<<2048, 256, 0, stream>>>(z, zt);
    screen_kernel<<<2048, 256, 0, stream>>>(zt, ebh, ebl, e2, z2, ts12, ts2);
    merge_kernel<<<N_PTS / 256, 256, 0, stream>>>(ts12, ts2, out_idx, cnt, light, heavy);
    light_kernel<<<512, 256, 0, stream>>>(z, emb, z2, e2, ts12, cnt, light, out_idx);
    heavy_kernel<<<256, 256, 0, stream>>>(z, emb, z2, e2, ts12, ts2, cnt, heavy, out_idx);
    gather_loss_kernel<<<N_ELEM / 1024, 256, 0, stream>>>(z, emb, out_idx, outf, partial);
    finalize_kernel<<<1, 64, 0, stream>>>(partial, out_loss);
}